// Round 1
// baseline (212.130 us; speedup 1.0000x reference)
//
#include <hip/hip_runtime.h>

// B=4, H=W=64, D=256, N=8, K=V=32, H2=W2=32, HW=4096, M=1024 pooled/batch.

typedef _Float16 f16x8 __attribute__((ext_vector_type(8)));
typedef _Float16 f16x4 __attribute__((ext_vector_type(4)));
typedef float    f32x4 __attribute__((ext_vector_type(4)));

#define F16(x) static_cast<_Float16>(x)

#if __has_builtin(__builtin_amdgcn_exp2f)
#define EXP2(x) __builtin_amdgcn_exp2f(x)
#else
#define EXP2(x) exp2f(x)
#endif

// ---------------- prep: weights -> f16 transposed Wt[mat][o][d] -------------
__global__ void prep_kernel(const float* __restrict__ wq, const float* __restrict__ wk,
                            const float* __restrict__ wv, _Float16* __restrict__ wt) {
    int idx = blockIdx.x * 256 + threadIdx.x;     // 196,608 exact
    int mat = idx >> 16;
    int r = idx & 65535;
    int d = r >> 8, o = r & 255;                  // coalesced read along o
    const float* w = (mat == 0) ? wq : (mat == 1 ? wk : wv);
    wt[(mat << 16) + o * 256 + d] = (_Float16)w[d * 256 + o];
}

// ---------------- proj: all three 1x1-conv GEMMs in one launch --------------
// block = 32 rows x 256 cols, 4 waves; wave = 32 rows x 64 cols (2 mc x 4 nt).
__global__ __launch_bounds__(256) void proj_kernel(
    const float* __restrict__ blob, const _Float16* __restrict__ wt,
    const float* __restrict__ bq, const float* __restrict__ bk, const float* __restrict__ bv,
    _Float16* __restrict__ qo, _Float16* __restrict__ ko, _Float16* __restrict__ vo) {
    const int lane = threadIdx.x & 63, wid = threadIdx.x >> 6;
    const int quad = lane >> 4, l16 = lane & 15;
    int jb = blockIdx.x;
    int job, rowblk;
    if (jb < 128)      { job = 0; rowblk = jb; }
    else if (jb < 640) { job = 1; rowblk = jb - 128; }
    else               { job = 2; rowblk = jb - 640; }
    const int rowbase = rowblk * 32;
    const int colbase = wid * 64;
    const _Float16* wmat = wt + ((size_t)job << 16);
    const float* bias = (job == 0) ? bq : (job == 1 ? bk : bv);

    f32x4 acc[2][4];   // [mc][nt]
#pragma unroll
    for (int mc = 0; mc < 2; ++mc)
#pragma unroll
        for (int nt = 0; nt < 4; ++nt) acc[mc][nt] = (f32x4){0.f, 0.f, 0.f, 0.f};

    const float* a0[2];
#pragma unroll
    for (int mc = 0; mc < 2; ++mc) {
        const int m = rowbase + mc * 16 + l16;
        if (job == 0) {
            const int bb = m >> 10, y = (m >> 5) & 31, x = m & 31;
            a0[mc] = blob + (((bb * 64 + 2 * y) * 64) + 2 * x) * 256;
        } else {
            a0[mc] = blob + (size_t)m * 256;
        }
    }

#pragma unroll 2
    for (int kc = 0; kc < 8; ++kc) {
        f16x8 bf[4];
#pragma unroll
        for (int nt = 0; nt < 4; ++nt)
            bf[nt] = *(const f16x8*)(wmat + (colbase + nt * 16 + l16) * 256 + kc * 32 + quad * 8);
#pragma unroll
        for (int mc = 0; mc < 2; ++mc) {
            const float* ap = a0[mc] + kc * 32 + quad * 8;
            float va[8];
            if (job == 0) {
                float4 p0 = *(const float4*)(ap);
                float4 p1 = *(const float4*)(ap + 4);
                float4 q0 = *(const float4*)(ap + 256);
                float4 q1 = *(const float4*)(ap + 260);
                float4 r0 = *(const float4*)(ap + 16384);
                float4 r1 = *(const float4*)(ap + 16388);
                float4 s0 = *(const float4*)(ap + 16640);
                float4 s1 = *(const float4*)(ap + 16644);
                va[0] = fmaxf(fmaxf(p0.x, q0.x), fmaxf(r0.x, s0.x));
                va[1] = fmaxf(fmaxf(p0.y, q0.y), fmaxf(r0.y, s0.y));
                va[2] = fmaxf(fmaxf(p0.z, q0.z), fmaxf(r0.z, s0.z));
                va[3] = fmaxf(fmaxf(p0.w, q0.w), fmaxf(r0.w, s0.w));
                va[4] = fmaxf(fmaxf(p1.x, q1.x), fmaxf(r1.x, s1.x));
                va[5] = fmaxf(fmaxf(p1.y, q1.y), fmaxf(r1.y, s1.y));
                va[6] = fmaxf(fmaxf(p1.z, q1.z), fmaxf(r1.z, s1.z));
                va[7] = fmaxf(fmaxf(p1.w, q1.w), fmaxf(r1.w, s1.w));
            } else {
                float4 f0 = *(const float4*)(ap);
                float4 f1 = *(const float4*)(ap + 4);
                va[0] = f0.x; va[1] = f0.y; va[2] = f0.z; va[3] = f0.w;
                va[4] = f1.x; va[5] = f1.y; va[6] = f1.z; va[7] = f1.w;
            }
            auto c0 = __builtin_amdgcn_cvt_pkrtz(va[0], va[1]);
            auto c1 = __builtin_amdgcn_cvt_pkrtz(va[2], va[3]);
            auto c2 = __builtin_amdgcn_cvt_pkrtz(va[4], va[5]);
            auto c3 = __builtin_amdgcn_cvt_pkrtz(va[6], va[7]);
            f16x8 af = {F16(c0[0]), F16(c0[1]), F16(c1[0]), F16(c1[1]),
                        F16(c2[0]), F16(c2[1]), F16(c3[0]), F16(c3[1])};
#pragma unroll
            for (int nt = 0; nt < 4; ++nt)
                acc[mc][nt] = __builtin_amdgcn_mfma_f32_16x16x32_f16(af, bf[nt], acc[mc][nt], 0, 0, 0);
        }
    }

#pragma unroll
    for (int nt = 0; nt < 4; ++nt) {
        const int o = colbase + nt * 16 + l16;
        const float bs = bias[o];
        const int nh = o >> 5, kk = o & 31;
#pragma unroll
        for (int mc = 0; mc < 2; ++mc) {
            if (job == 0) {
#pragma unroll
                for (int r = 0; r < 4; ++r) {
                    const int grow = rowbase + mc * 16 + quad * 4 + r;
                    // scale = (1/sqrt(32)) * log2(e): attn uses exp2
                    const float x = (acc[mc][nt][r] + bs) * 0.25503508f;
                    const int bb = grow >> 10, mm = grow & 1023;
                    qo[(((bb * 8 + nh) * 1024 + mm) << 5) + kk] = (_Float16)x;
                }
            } else if (job == 1) {
#pragma unroll
                for (int r = 0; r < 4; ++r) {
                    const int grow = rowbase + mc * 16 + quad * 4 + r;
                    const float x = acc[mc][nt][r] + bs;
                    const int bb = grow >> 12, ii = grow & 4095;
                    ko[(((bb * 8 + nh) * 4096 + ii) << 5) + kk] = (_Float16)x;
                }
            } else {
                const int grow0 = rowbase + mc * 16 + quad * 4;
                const int bb = grow0 >> 12, i0 = grow0 & 4095;
                f16x4 pv;
#pragma unroll
                for (int r = 0; r < 4; ++r) {
                    float x = acc[mc][nt][r] + bs;
                    const float sg = 1.0f / (1.0f + __expf(-x));
                    pv[r] = (_Float16)(x * sg);
                }
                *(f16x4*)(vo + (((size_t)(bb * 8 + nh) * 32 + kk) << 12) + i0) = pv;
            }
        }
    }
}

// ---------------- attn: no LDS staging — K/V stream straight from L2 --------
// K/V per bn = 512 KB, L2-resident (FETCH_SIZE showed 9 MB vs 256 MB of reads).
// grid 1024 = 32 bn (XCD swizzle: bn%8 == XCD) x 32 mt; block = 8 waves.
// Wave w = key-stream kc = w: keys [kc*512, kc*512+512), all 32 q-rows of the
// block. No barriers in the main loop; 8-way key-split combined in a 4.4 KB
// LDS epilogue. 512 thr + <=64 VGPR + tiny LDS -> 4 blocks/CU = 8 waves/SIMD
// (2x the old LDS-staged kernel's occupancy).
// Fragment lane-maps identical to the verified LDS version:
//   kf : A of 16x16x32, lane(l16,quad) = K[key=t*16+l16][elem quad*8..+7]
//        -> wave load = 1 KB fully contiguous from kb[bn][key][elem].
//   va : A of 16x16x16, lane(l16,quad)[r] = V^T[vc*16+l16][key0+quad*4+r]
//        -> 16 segments x 32 B from vt[bn][v][key], L2-hit.
__global__ __launch_bounds__(512, 8) void attn_kernel(
    const _Float16* __restrict__ qb,   // [32][1024][32] (pre-scaled log2e/sqrt32)
    const _Float16* __restrict__ kb,   // [32][4096][32]
    const _Float16* __restrict__ vt,   // [32][32][4096]  (V^T)
    float* __restrict__ out) {         // [4][1024][256]
    __shared__ float pool[32 * 33 + 32];   // num[32][33] | den[32]

    const int tid = threadIdx.x;
    const int lane = tid & 63, kc = tid >> 6;
    const int quad = lane >> 4, l16 = lane & 15;
    const int bn = blockIdx.x & 31, mt = blockIdx.x >> 5;
    const int b = bn >> 3, n = bn & 7;
    const int m0 = mt * 32;

    // zero the combine buffer now; first barrier is after the main loop
    for (int i = tid; i < 32 * 33 + 32; i += 512) pool[i] = 0.f;

    // Q fragments (L2-hot, loaded once)
    f16x8 qf[2];
#pragma unroll
    for (int mc = 0; mc < 2; ++mc)
        qf[mc] = *(const f16x8*)(qb + (((size_t)(bn << 10) + m0 + mc * 16 + l16) << 5) + quad * 8);

    const size_t bnoff = (size_t)bn << 17;
    const _Float16* kp  = kb + bnoff + (size_t)(kc * 512 + l16) * 32 + quad * 8;
    const _Float16* vp0 = vt + bnoff + (size_t)l16 * 4096 + kc * 512 + quad * 4;
    const _Float16* vp1 = vp0 + (size_t)16 * 4096;

    f32x4 acc[2][2];   // [mc][vc]: out^T[v=vc*16+quad*4+r][m=m0+mc*16+l16]
    acc[0][0] = (f32x4){0.f, 0.f, 0.f, 0.f}; acc[0][1] = acc[0][0];
    acc[1][0] = acc[0][0];                    acc[1][1] = acc[0][0];
    float ps0 = 0.f, ps1 = 0.f;

#pragma unroll 4
    for (int t = 0; t < 32; ++t) {            // 32 x 16 keys = 512 keys/wave
        const f16x8 kf  = *(const f16x8*)(kp);  kp  += 512;   // next 16 keys
        const f16x4 va0 = *(const f16x4*)(vp0); vp0 += 16;
        const f16x4 va1 = *(const f16x4*)(vp1); vp1 += 16;

        f32x4 s0 = __builtin_amdgcn_mfma_f32_16x16x32_f16(kf, qf[0], (f32x4){0.f,0.f,0.f,0.f}, 0, 0, 0);
        f32x4 s1 = __builtin_amdgcn_mfma_f32_16x16x32_f16(kf, qf[1], (f32x4){0.f,0.f,0.f,0.f}, 0, 0, 0);
        const float p0 = EXP2(s0[0]), p1 = EXP2(s0[1]), p2 = EXP2(s0[2]), p3 = EXP2(s0[3]);
        const float u0 = EXP2(s1[0]), u1 = EXP2(s1[1]), u2 = EXP2(s1[2]), u3 = EXP2(s1[3]);
        ps0 += (p0 + p1) + (p2 + p3);
        ps1 += (u0 + u1) + (u2 + u3);
        auto e0 = __builtin_amdgcn_cvt_pkrtz(p0, p1);
        auto e1 = __builtin_amdgcn_cvt_pkrtz(p2, p3);
        auto e2 = __builtin_amdgcn_cvt_pkrtz(u0, u1);
        auto e3 = __builtin_amdgcn_cvt_pkrtz(u2, u3);
        const f16x4 pb0 = {F16(e0[0]), F16(e0[1]), F16(e1[0]), F16(e1[1])};
        const f16x4 pb1 = {F16(e2[0]), F16(e2[1]), F16(e3[0]), F16(e3[1])};
        acc[0][0] = __builtin_amdgcn_mfma_f32_16x16x16f16(va0, pb0, acc[0][0], 0, 0, 0);
        acc[0][1] = __builtin_amdgcn_mfma_f32_16x16x16f16(va1, pb0, acc[0][1], 0, 0, 0);
        acc[1][0] = __builtin_amdgcn_mfma_f32_16x16x16f16(va0, pb1, acc[1][0], 0, 0, 0);
        acc[1][1] = __builtin_amdgcn_mfma_f32_16x16x16f16(va1, pb1, acc[1][1], 0, 0, 0);
    }

    // ---- epilogue: 8-way key-split combine in LDS ----
    float* num = pool;             // [32][33]
    float* den = pool + 32 * 33;   // [32]

    // sum exp-partials over the 4 quads (score rows live in quads)
    ps0 += __shfl_xor(ps0, 16); ps0 += __shfl_xor(ps0, 32);
    ps1 += __shfl_xor(ps1, 16); ps1 += __shfl_xor(ps1, 32);

    __syncthreads();   // zeros visible + all waves done computing

#pragma unroll
    for (int mc = 0; mc < 2; ++mc) {
        const int m = mc * 16 + l16;
#pragma unroll
        for (int vc = 0; vc < 2; ++vc)
#pragma unroll
            for (int r = 0; r < 4; ++r)
                atomicAdd(&num[m * 33 + vc * 16 + quad * 4 + r], acc[mc][vc][r]);
    }
    if (quad == 0) {
        atomicAdd(&den[l16], ps0);
        atomicAdd(&den[16 + l16], ps1);
    }
    __syncthreads();

    // store: 32 m x 32 v = 1024 f32 = 512 threads x one float2
    {
        const int mloc = tid >> 4, v2 = (tid & 15) * 2;
        const float inv = 1.0f / den[mloc];
        const float* nr = num + mloc * 33 + v2;
        float2 o = {nr[0] * inv, nr[1] * inv};
        *(float2*)(out + (((size_t)(b << 10) + m0 + mloc) << 8) + n * 32 + v2) = o;
    }
}

// ---------------- launch -----------------------------------------------------
extern "C" void kernel_launch(void* const* d_in, const int* in_sizes, int n_in,
                              void* d_out, int out_size, void* d_ws, size_t ws_size,
                              hipStream_t stream) {
    const float* blob = (const float*)d_in[0];
    const float* wq = (const float*)d_in[1];
    const float* bq = (const float*)d_in[2];
    const float* wk = (const float*)d_in[3];
    const float* bk = (const float*)d_in[4];
    const float* wv = (const float*)d_in[5];
    const float* bv = (const float*)d_in[6];
    float* out = (float*)d_out;

    char* ws = (char*)d_ws;
    _Float16* wt = (_Float16*)(ws);                    //   393,216 B
    _Float16* ko = (_Float16*)(ws + 393216);           // 8,388,608 B
    _Float16* vo = (_Float16*)(ws + 8781824);          // 8,388,608 B
    _Float16* qo = (_Float16*)(ws + 17170432);         // 2,097,152 B

    prep_kernel<<<768, 256, 0, stream>>>(wq, wk, wv, wt);
    proj_kernel<<<1152, 256, 0, stream>>>(blob, wt, bq, bk, bv, qo, ko, vo);
    attn_kernel<<<1024, 512, 0, stream>>>(qo, ko, vo, out);
}

// Round 2
// 161.623 us; speedup vs baseline: 1.3125x; 1.3125x over previous
//
#include <hip/hip_runtime.h>

// B=4, H=W=64, D=256, N=8, K=V=32, H2=W2=32, HW=4096, M=1024 pooled/batch.

typedef _Float16 f16x8 __attribute__((ext_vector_type(8)));
typedef _Float16 f16x4 __attribute__((ext_vector_type(4)));
typedef float    f32x4 __attribute__((ext_vector_type(4)));

#define F16(x) static_cast<_Float16>(x)

#if __has_builtin(__builtin_amdgcn_exp2f)
#define EXP2(x) __builtin_amdgcn_exp2f(x)
#else
#define EXP2(x) exp2f(x)
#endif

// async global->LDS DMA, 16 B per lane; lane i lands at ldsbase + i*16
__device__ __forceinline__ void gl_lds16(const void* g, void* l) {
    __builtin_amdgcn_global_load_lds(
        (const __attribute__((address_space(1))) unsigned int*)g,
        (__attribute__((address_space(3))) unsigned int*)l, 16, 0, 0);
}

// ---------------- prep: weights -> f16 transposed Wt[mat][o][d] -------------
// LDS 32x33 tile transpose: coalesced f32 reads along o, contiguous f16
// writes along d (old version wrote 2B at stride 512B -> 64 lines/wave).
__global__ __launch_bounds__(256) void prep_kernel(
    const float* __restrict__ wq, const float* __restrict__ wk,
    const float* __restrict__ wv, _Float16* __restrict__ wt) {
    __shared__ float t[32][33];
    const int blk = blockIdx.x;              // 192 = 3 mats x 64 tiles
    const int mat = blk >> 6;
    const int tile = blk & 63;
    const int d0 = (tile >> 3) * 32, o0 = (tile & 7) * 32;
    const float* w = (mat == 0) ? wq : (mat == 1 ? wk : wv);
    const int tx = threadIdx.x & 31, ty = threadIdx.x >> 5;   // ty 0..7
#pragma unroll
    for (int i = 0; i < 4; ++i)
        t[ty + i * 8][tx] = w[(d0 + ty + i * 8) * 256 + o0 + tx];
    __syncthreads();
#pragma unroll
    for (int i = 0; i < 4; ++i)
        wt[(mat << 16) + (o0 + ty + i * 8) * 256 + d0 + tx] = (_Float16)t[tx][ty + i * 8];
}

// ---------------- proj: all three 1x1-conv GEMMs in one launch --------------
// block = 32 rows x 256 cols, 4 waves; wave = 32 rows x 64 cols (2 mc x 4 nt).
__global__ __launch_bounds__(256) void proj_kernel(
    const float* __restrict__ blob, const _Float16* __restrict__ wt,
    const float* __restrict__ bq, const float* __restrict__ bk, const float* __restrict__ bv,
    _Float16* __restrict__ qo, _Float16* __restrict__ ko, _Float16* __restrict__ vo) {
    const int lane = threadIdx.x & 63, wid = threadIdx.x >> 6;
    const int quad = lane >> 4, l16 = lane & 15;
    int jb = blockIdx.x;
    int job, rowblk;
    if (jb < 128)      { job = 0; rowblk = jb; }
    else if (jb < 640) { job = 1; rowblk = jb - 128; }
    else               { job = 2; rowblk = jb - 640; }
    const int rowbase = rowblk * 32;
    const int colbase = wid * 64;
    const _Float16* wmat = wt + ((size_t)job << 16);
    const float* bias = (job == 0) ? bq : (job == 1 ? bk : bv);

    f32x4 acc[2][4];   // [mc][nt]
#pragma unroll
    for (int mc = 0; mc < 2; ++mc)
#pragma unroll
        for (int nt = 0; nt < 4; ++nt) acc[mc][nt] = (f32x4){0.f, 0.f, 0.f, 0.f};

    const float* a0[2];
#pragma unroll
    for (int mc = 0; mc < 2; ++mc) {
        const int m = rowbase + mc * 16 + l16;
        if (job == 0) {
            const int bb = m >> 10, y = (m >> 5) & 31, x = m & 31;
            a0[mc] = blob + (((bb * 64 + 2 * y) * 64) + 2 * x) * 256;
        } else {
            a0[mc] = blob + (size_t)m * 256;
        }
    }

#pragma unroll 2
    for (int kc = 0; kc < 8; ++kc) {
        f16x8 bf[4];
#pragma unroll
        for (int nt = 0; nt < 4; ++nt)
            bf[nt] = *(const f16x8*)(wmat + (colbase + nt * 16 + l16) * 256 + kc * 32 + quad * 8);
#pragma unroll
        for (int mc = 0; mc < 2; ++mc) {
            const float* ap = a0[mc] + kc * 32 + quad * 8;
            float va[8];
            if (job == 0) {
                float4 p0 = *(const float4*)(ap);
                float4 p1 = *(const float4*)(ap + 4);
                float4 q0 = *(const float4*)(ap + 256);
                float4 q1 = *(const float4*)(ap + 260);
                float4 r0 = *(const float4*)(ap + 16384);
                float4 r1 = *(const float4*)(ap + 16388);
                float4 s0 = *(const float4*)(ap + 16640);
                float4 s1 = *(const float4*)(ap + 16644);
                va[0] = fmaxf(fmaxf(p0.x, q0.x), fmaxf(r0.x, s0.x));
                va[1] = fmaxf(fmaxf(p0.y, q0.y), fmaxf(r0.y, s0.y));
                va[2] = fmaxf(fmaxf(p0.z, q0.z), fmaxf(r0.z, s0.z));
                va[3] = fmaxf(fmaxf(p0.w, q0.w), fmaxf(r0.w, s0.w));
                va[4] = fmaxf(fmaxf(p1.x, q1.x), fmaxf(r1.x, s1.x));
                va[5] = fmaxf(fmaxf(p1.y, q1.y), fmaxf(r1.y, s1.y));
                va[6] = fmaxf(fmaxf(p1.z, q1.z), fmaxf(r1.z, s1.z));
                va[7] = fmaxf(fmaxf(p1.w, q1.w), fmaxf(r1.w, s1.w));
            } else {
                float4 f0 = *(const float4*)(ap);
                float4 f1 = *(const float4*)(ap + 4);
                va[0] = f0.x; va[1] = f0.y; va[2] = f0.z; va[3] = f0.w;
                va[4] = f1.x; va[5] = f1.y; va[6] = f1.z; va[7] = f1.w;
            }
            auto c0 = __builtin_amdgcn_cvt_pkrtz(va[0], va[1]);
            auto c1 = __builtin_amdgcn_cvt_pkrtz(va[2], va[3]);
            auto c2 = __builtin_amdgcn_cvt_pkrtz(va[4], va[5]);
            auto c3 = __builtin_amdgcn_cvt_pkrtz(va[6], va[7]);
            f16x8 af = {F16(c0[0]), F16(c0[1]), F16(c1[0]), F16(c1[1]),
                        F16(c2[0]), F16(c2[1]), F16(c3[0]), F16(c3[1])};
#pragma unroll
            for (int nt = 0; nt < 4; ++nt)
                acc[mc][nt] = __builtin_amdgcn_mfma_f32_16x16x32_f16(af, bf[nt], acc[mc][nt], 0, 0, 0);
        }
    }

#pragma unroll
    for (int nt = 0; nt < 4; ++nt) {
        const int o = colbase + nt * 16 + l16;
        const float bs = bias[o];
        const int nh = o >> 5, kk = o & 31;
#pragma unroll
        for (int mc = 0; mc < 2; ++mc) {
            if (job == 0) {
#pragma unroll
                for (int r = 0; r < 4; ++r) {
                    const int grow = rowbase + mc * 16 + quad * 4 + r;
                    // scale = (1/sqrt(32)) * log2(e): attn uses exp2
                    const float x = (acc[mc][nt][r] + bs) * 0.25503508f;
                    const int bb = grow >> 10, mm = grow & 1023;
                    qo[(((bb * 8 + nh) * 1024 + mm) << 5) + kk] = (_Float16)x;
                }
            } else if (job == 1) {
#pragma unroll
                for (int r = 0; r < 4; ++r) {
                    const int grow = rowbase + mc * 16 + quad * 4 + r;
                    const float x = acc[mc][nt][r] + bs;
                    const int bb = grow >> 12, ii = grow & 4095;
                    ko[(((bb * 8 + nh) * 4096 + ii) << 5) + kk] = (_Float16)x;
                }
            } else {
                const int grow0 = rowbase + mc * 16 + quad * 4;
                const int bb = grow0 >> 12, i0 = grow0 & 4095;
                f16x4 pv;
#pragma unroll
                for (int r = 0; r < 4; ++r) {
                    float x = acc[mc][nt][r] + bs;
                    const float sg = 1.0f / (1.0f + __expf(-x));
                    pv[r] = (_Float16)(x * sg);
                }
                *(f16x4*)(vo + (((size_t)(bb * 8 + nh) * 32 + kk) << 12) + i0) = pv;
            }
        }
    }
}

// ---------------- attn: LDS K/V, triple-buffered counted-vmcnt pipeline -----
// grid 512 = 32 bn (XCD swizzle: bn%8==XCD) x 16 mt; block = 8 waves, 64 rows.
// wave (rg=wid&3, kc=wid>>2): q-rows [m0+rg*16,+16), keys [kc*2048,+2048).
// 2 K/V streams, each TRIPLE-buffered 64-key tiles (32 steps):
//   stream base kc*24576 + buf*8192: K tile 4 KB | V tile 4 KB.
// Per step each wave issues 2 gl_lds16 for step s+2, computes step s, then
//   s_waitcnt vmcnt(2) + s_barrier  (raw asm: __syncthreads would re-drain
//   vmcnt to 0 and kill the lookahead -- the m97 barrier-drain stall).
// Step s+1's loads were issued a full step earlier -> wait is free.
// K granule (k,c) -> slot k*4 + ((c + (k>>2))&3)  (conflict-free b128 reads)
// V granule (v,c) -> slot v*8 + ((c+v)&7)         (conflict-free b64 reads)
// (both layouts byte-identical to the verified round-0 kernel)
__global__ __launch_bounds__(512, 4) void attn_kernel(
    const _Float16* __restrict__ qb,   // [32][1024][32] (pre-scaled log2e/sqrt32)
    const _Float16* __restrict__ kb,   // [32][4096][32]
    const _Float16* __restrict__ vt,   // [32][32][4096]  (V^T)
    float* __restrict__ out) {         // [4][1024][256]
    __shared__ __align__(16) char pool[49152];   // 2 streams x 3 bufs x 8 KB

    const int tid = threadIdx.x;
    const int lane = tid & 63, wid = tid >> 6;
    const int quad = lane >> 4, l16 = lane & 15;
    const int bn = blockIdx.x & 31, mt = blockIdx.x >> 5;
    const int b = bn >> 3, n = bn & 7;
    const int m0 = mt * 64;
    const int rg = wid & 3, kc = wid >> 2;

    // ---- per-wave DMA assignments: 2 wave-loads (1 KB each) per step ----
    const _Float16* gsrc[2];
    int ldsoff[2], adv[2];
#pragma unroll
    for (int jj = 0; jj < 2; ++jj) {
        const int j = wid + jj * 8;              // 0..15
        const int kcj = j >> 3, sub = j & 7;
        const int gl = (sub & 3) * 64 + lane;    // granule slot in K or V region
        if (sub < 4) {   // K region: invert slot = k*4 + ((c + (k>>2))&3)
            const int k = gl >> 2, c = ((gl & 3) - (k >> 2)) & 3;
            gsrc[jj]   = kb + ((size_t)bn << 17) + (size_t)(kcj * 2048 + k) * 32 + c * 8;
            ldsoff[jj] = kcj * 24576 + gl * 16;
            adv[jj] = 2048;                      // 64 keys * 32 elems per step
        } else {         // V region: invert slot = v*8 + ((c+v)&7)
            const int v = gl >> 3, c = ((gl & 7) - v) & 7;
            gsrc[jj]   = vt + ((size_t)bn << 17) + (size_t)v * 4096 + kcj * 2048 + c * 8;
            ldsoff[jj] = kcj * 24576 + 4096 + gl * 16;
            adv[jj] = 64;                        // 64 keys per step
        }
    }

    // Q fragment (16 rows, L2-hot)
    const f16x8 qf = *(const f16x8*)(qb + (((size_t)(bn << 10) + m0 + rg * 16 + l16) << 5) + quad * 8);

    // per-lane read bases (K read swizzle is tloc-invariant by construction)
    const int kread = kc * 24576 + l16 * 64 + ((quad + (l16 >> 2)) & 3) * 16;
    const int vread = kc * 24576 + 4096 + l16 * 128 + (quad & 1) * 8;
    const int r0 = (quad >> 1) + l16;

    // prologue: DMA steps 0,1 into bufs 0,1
#pragma unroll
    for (int p = 0; p < 2; ++p)
#pragma unroll
        for (int jj = 0; jj < 2; ++jj) {
            gl_lds16(gsrc[jj], pool + ldsoff[jj] + p * 8192);
            gsrc[jj] += adv[jj];
        }
    asm volatile("s_waitcnt vmcnt(2)\n\ts_barrier" ::: "memory");   // step 0 ready

    f32x4 acc0 = (f32x4){0.f, 0.f, 0.f, 0.f};   // out^T[v=quad*4+r   ][m=rg*16+l16]
    f32x4 acc1 = acc0;                           // out^T[v=16+quad*4+r][m=rg*16+l16]
    float ps0 = 0.f;

    for (int s = 0; s < 32; ++s) {
        if (s < 30) {   // DMA step s+2 into buffer (s+2)%3
            const int nb = ((s + 2) % 3) * 8192;
#pragma unroll
            for (int jj = 0; jj < 2; ++jj) {
                gl_lds16(gsrc[jj], pool + ldsoff[jj] + nb);
                gsrc[jj] += adv[jj];
            }
        }
        const char* kbase = pool + kread + (s % 3) * 8192;
        const char* vbase = pool + vread + (s % 3) * 8192;
#pragma unroll
        for (int tloc = 0; tloc < 4; ++tloc) {
            const f16x8 kf = *(const f16x8*)(kbase + tloc * 1024);
            const int rot = ((2 * tloc + r0) & 7) * 16;
            const f16x4 va0 = *(const f16x4*)(vbase + rot);
            const f16x4 va1 = *(const f16x4*)(vbase + rot + 2048);

            f32x4 s0 = __builtin_amdgcn_mfma_f32_16x16x32_f16(kf, qf, (f32x4){0.f,0.f,0.f,0.f}, 0, 0, 0);
            const float p0 = EXP2(s0[0]), p1 = EXP2(s0[1]), p2 = EXP2(s0[2]), p3 = EXP2(s0[3]);
            ps0 += (p0 + p1) + (p2 + p3);
            auto e0 = __builtin_amdgcn_cvt_pkrtz(p0, p1);
            auto e1 = __builtin_amdgcn_cvt_pkrtz(p2, p3);
            const f16x4 pb = {F16(e0[0]), F16(e0[1]), F16(e1[0]), F16(e1[1])};
            acc0 = __builtin_amdgcn_mfma_f32_16x16x16f16(va0, pb, acc0, 0, 0, 0);
            acc1 = __builtin_amdgcn_mfma_f32_16x16x16f16(va1, pb, acc1, 0, 0, 0);
        }
        // wait for step s+1's loads (issued one full step ago), keep s+2's 2
        // loads in flight across the barrier
        if (s < 30)       asm volatile("s_waitcnt vmcnt(2)\n\ts_barrier" ::: "memory");
        else if (s == 30) asm volatile("s_waitcnt vmcnt(0)\n\ts_barrier" ::: "memory");
        else              asm volatile("s_barrier" ::: "memory");
    }

    // ---- epilogue: 2-way key-split combine in (now free) LDS ----
    float* num = (float*)pool;                 // [64][33]
    float* den = (float*)(pool + 64 * 33 * 4); // [64]
    for (int i = tid; i < 64 * 33 + 64; i += 512) ((float*)pool)[i] = 0.f;
    __syncthreads();

    // sum exp-partials over the 4 quads (score rows live in quads)
    ps0 += __shfl_xor(ps0, 16); ps0 += __shfl_xor(ps0, 32);

    const int m = rg * 16 + l16;
#pragma unroll
    for (int r = 0; r < 4; ++r) {
        atomicAdd(&num[m * 33 + quad * 4 + r], acc0[r]);
        atomicAdd(&num[m * 33 + 16 + quad * 4 + r], acc1[r]);
    }
    if (quad == 0) atomicAdd(&den[m], ps0);
    __syncthreads();

    // store: 64 m x 32 v = 2048 f32 = 512 threads x one float4
    {
        const int mloc = tid >> 3, v4 = (tid & 7) * 4;
        const float inv = 1.0f / den[mloc];
        const float* nr = num + mloc * 33 + v4;
        float4 o = {nr[0] * inv, nr[1] * inv, nr[2] * inv, nr[3] * inv};
        *(float4*)(out + (((size_t)(b << 10) + m0 + mloc) << 8) + n * 32 + v4) = o;
    }
}

// ---------------- launch -----------------------------------------------------
extern "C" void kernel_launch(void* const* d_in, const int* in_sizes, int n_in,
                              void* d_out, int out_size, void* d_ws, size_t ws_size,
                              hipStream_t stream) {
    const float* blob = (const float*)d_in[0];
    const float* wq = (const float*)d_in[1];
    const float* bq = (const float*)d_in[2];
    const float* wk = (const float*)d_in[3];
    const float* bk = (const float*)d_in[4];
    const float* wv = (const float*)d_in[5];
    const float* bv = (const float*)d_in[6];
    float* out = (float*)d_out;

    char* ws = (char*)d_ws;
    _Float16* wt = (_Float16*)(ws);                    //   393,216 B
    _Float16* ko = (_Float16*)(ws + 393216);           // 8,388,608 B
    _Float16* vo = (_Float16*)(ws + 8781824);          // 8,388,608 B
    _Float16* qo = (_Float16*)(ws + 17170432);         // 2,097,152 B

    prep_kernel<<<192, 256, 0, stream>>>(wq, wk, wv, wt);
    proj_kernel<<<1152, 256, 0, stream>>>(blob, wt, bq, bk, bv, qo, ko, vo);
    attn_kernel<<<512, 512, 0, stream>>>(qo, ko, vo, out);
}

// Round 3
// 137.240 us; speedup vs baseline: 1.5457x; 1.1777x over previous
//
#include <hip/hip_runtime.h>

// B=4, H=W=64, D=256, N=8, K=V=32, H2=W2=32, HW=4096, M=1024 pooled/batch.

typedef _Float16 f16x8 __attribute__((ext_vector_type(8)));
typedef _Float16 f16x4 __attribute__((ext_vector_type(4)));
typedef float    f32x4 __attribute__((ext_vector_type(4)));

#define F16(x) static_cast<_Float16>(x)

#if __has_builtin(__builtin_amdgcn_exp2f)
#define EXP2(x) __builtin_amdgcn_exp2f(x)
#else
#define EXP2(x) exp2f(x)
#endif

// async global->LDS DMA, 16 B per lane; lane i lands at ldsbase + i*16
__device__ __forceinline__ void gl_lds16(const void* g, void* l) {
    __builtin_amdgcn_global_load_lds(
        (const __attribute__((address_space(1))) unsigned int*)g,
        (__attribute__((address_space(3))) unsigned int*)l, 16, 0, 0);
}

// ---------------- prep: weights -> f16 transposed Wt[mat][o][d] -------------
// LDS 32x33 tile transpose: coalesced f32 reads along o, contiguous f16
// writes along d.
__global__ __launch_bounds__(256) void prep_kernel(
    const float* __restrict__ wq, const float* __restrict__ wk,
    const float* __restrict__ wv, _Float16* __restrict__ wt) {
    __shared__ float t[32][33];
    const int blk = blockIdx.x;              // 192 = 3 mats x 64 tiles
    const int mat = blk >> 6;
    const int tile = blk & 63;
    const int d0 = (tile >> 3) * 32, o0 = (tile & 7) * 32;
    const float* w = (mat == 0) ? wq : (mat == 1 ? wk : wv);
    const int tx = threadIdx.x & 31, ty = threadIdx.x >> 5;   // ty 0..7
#pragma unroll
    for (int i = 0; i < 4; ++i)
        t[ty + i * 8][tx] = w[(d0 + ty + i * 8) * 256 + o0 + tx];
    __syncthreads();
#pragma unroll
    for (int i = 0; i < 4; ++i)
        wt[(mat << 16) + (o0 + ty + i * 8) * 256 + d0 + tx] = (_Float16)t[tx][ty + i * 8];
}

// ---------------- proj: all three 1x1-conv GEMMs in one launch --------------
// block = 64 rows x 256 cols, 4 waves; wave = ALL 64 rows x 64 cols
// (4 mc x 4 nt, acc 64 VGPR, 16 MFMA per K-step).
// A (blob rows) is shared by all 4 waves -> staged once per block in LDS as
// f16, double-buffered 2 x 4 KB, depth-2 pipeline:
//   epoch s: COMPUTE(s) [ds_read af + reg-prefetched weights] ;
//            WRITE(s+1) [cvt regs loaded at s-1 -> ds_write_b128] ;
//            LOAD(s+2)  [global f32 loads into regs] ;
//            lgkmcnt(0) + raw s_barrier  (keeps loads in flight across it).
// A-tile granule (r,c) -> slot r*4 + ((c + (r>>2))&3): the attn-verified
// conflict-free layout for ds_read_b128 of [rows][32-elem] f16 tiles.
// Weights: per-wave 4 x f16x8 per step, register-double-buffered (prefetch
// s+1 during compute s).  Fully unrolled so all ping-pong indices fold.
__global__ __launch_bounds__(256) void proj_kernel(
    const float* __restrict__ blob, const _Float16* __restrict__ wt,
    const float* __restrict__ bq, const float* __restrict__ bk, const float* __restrict__ bv,
    _Float16* __restrict__ qo, _Float16* __restrict__ ko, _Float16* __restrict__ vo) {
    __shared__ __align__(16) char atile[2][4096];   // [buf][64 rows x 32 k f16]

    const int tid = threadIdx.x;
    const int lane = tid & 63, wid = tid >> 6;
    const int quad = lane >> 4, l16 = lane & 15;
    int jb = blockIdx.x;                     // 576 = 64 q + 256 k + 256 v
    int job, rowblk;
    if (jb < 64)       { job = 0; rowblk = jb; }
    else if (jb < 320) { job = 1; rowblk = jb - 64; }
    else               { job = 2; rowblk = jb - 320; }
    const int rowbase = rowblk * 64;
    const int colbase = wid * 64;
    const _Float16* wmat = wt + ((size_t)job << 16);
    const float* bias = (job == 0) ? bq : (job == 1 ? bk : bv);

    // ---- staging assignment: 256 threads x 16 B granule of the A tile ----
    const int srow = tid >> 2, sc8 = tid & 3;            // row 0..63, 8-elem col
    const int sslot = srow * 4 + ((sc8 + (srow >> 2)) & 3);
    const float* aptr;                                    // global src base
    if (job == 0) {
        const int grow = rowbase + srow;
        const int bb = grow >> 10, y = (grow >> 5) & 31, x = grow & 31;
        aptr = blob + (((bb * 64 + 2 * y) * 64) + 2 * x) * 256 + sc8 * 8;
    } else {
        aptr = blob + (size_t)(rowbase + srow) * 256 + sc8 * 8;
    }

    // per-wave weight pointers
    const _Float16* wptr[4];
#pragma unroll
    for (int nt = 0; nt < 4; ++nt)
        wptr[nt] = wmat + (size_t)(colbase + nt * 16 + l16) * 256 + quad * 8;

    // af read base (per-lane, swizzled; mc adds 1024 B)
    const int aread = l16 * 64 + ((quad + (l16 >> 2)) & 3) * 16;

    f32x4 acc[4][4];
#pragma unroll
    for (int mc = 0; mc < 4; ++mc)
#pragma unroll
        for (int nt = 0; nt < 4; ++nt) acc[mc][nt] = (f32x4){0.f, 0.f, 0.f, 0.f};

    f16x8 wf[2][4];      // weight double-buffer
    float4 ar[2][2];     // A-load double-buffer (8 f32 = one 16 B granule)

    // LOAD(t): global f32 -> regs (job0: 2x2 window max, eager)
    auto A_LOAD = [&](int t, float4* dst) {
        const float* p = aptr + t * 32;
        if (job == 0) {
            float4 a0 = *(const float4*)(p);
            float4 a1 = *(const float4*)(p + 4);
            float4 b0 = *(const float4*)(p + 256);
            float4 b1 = *(const float4*)(p + 260);
            float4 c0 = *(const float4*)(p + 16384);
            float4 c1 = *(const float4*)(p + 16388);
            float4 d0 = *(const float4*)(p + 16640);
            float4 d1 = *(const float4*)(p + 16644);
            dst[0].x = fmaxf(fmaxf(a0.x, b0.x), fmaxf(c0.x, d0.x));
            dst[0].y = fmaxf(fmaxf(a0.y, b0.y), fmaxf(c0.y, d0.y));
            dst[0].z = fmaxf(fmaxf(a0.z, b0.z), fmaxf(c0.z, d0.z));
            dst[0].w = fmaxf(fmaxf(a0.w, b0.w), fmaxf(c0.w, d0.w));
            dst[1].x = fmaxf(fmaxf(a1.x, b1.x), fmaxf(c1.x, d1.x));
            dst[1].y = fmaxf(fmaxf(a1.y, b1.y), fmaxf(c1.y, d1.y));
            dst[1].z = fmaxf(fmaxf(a1.z, b1.z), fmaxf(c1.z, d1.z));
            dst[1].w = fmaxf(fmaxf(a1.w, b1.w), fmaxf(c1.w, d1.w));
        } else {
            dst[0] = *(const float4*)(p);
            dst[1] = *(const float4*)(p + 4);
        }
    };
    // WRITE(t): cvt regs -> ds_write_b128 into buf t&1
    auto A_WRITE = [&](int buf, const float4* src) {
        auto c0 = __builtin_amdgcn_cvt_pkrtz(src[0].x, src[0].y);
        auto c1 = __builtin_amdgcn_cvt_pkrtz(src[0].z, src[0].w);
        auto c2 = __builtin_amdgcn_cvt_pkrtz(src[1].x, src[1].y);
        auto c3 = __builtin_amdgcn_cvt_pkrtz(src[1].z, src[1].w);
        f16x8 v = {F16(c0[0]), F16(c0[1]), F16(c1[0]), F16(c1[1]),
                   F16(c2[0]), F16(c2[1]), F16(c3[0]), F16(c3[1])};
        *(f16x8*)(atile[buf] + sslot * 16) = v;
    };
    auto W_LOAD = [&](int t, f16x8* dst) {
#pragma unroll
        for (int nt = 0; nt < 4; ++nt) dst[nt] = *(const f16x8*)(wptr[nt] + t * 32);
    };

    // ---- prologue ----
    W_LOAD(0, wf[0]);
    A_LOAD(0, ar[0]);
    A_WRITE(0, ar[0]);
    A_LOAD(1, ar[1]);
    asm volatile("s_waitcnt lgkmcnt(0)\n\ts_barrier" ::: "memory");

#pragma unroll
    for (int s = 0; s < 8; ++s) {
        // compute epoch s
        if (s < 7) W_LOAD(s + 1, wf[(s + 1) & 1]);
        f16x8 af[4];
#pragma unroll
        for (int mc = 0; mc < 4; ++mc)
            af[mc] = *(const f16x8*)(atile[s & 1] + mc * 1024 + aread);
#pragma unroll
        for (int mc = 0; mc < 4; ++mc)
#pragma unroll
            for (int nt = 0; nt < 4; ++nt)
                acc[mc][nt] = __builtin_amdgcn_mfma_f32_16x16x32_f16(
                    af[mc], wf[s & 1][nt], acc[mc][nt], 0, 0, 0);
        if (s < 7) A_WRITE((s + 1) & 1, ar[(s + 1) & 1]);
        if (s < 6) A_LOAD(s + 2, ar[s & 1]);
        if (s < 7) asm volatile("s_waitcnt lgkmcnt(0)\n\ts_barrier" ::: "memory");
    }

    // ---- epilogue: bias / scale / swish + stores (mapping as verified) ----
#pragma unroll
    for (int nt = 0; nt < 4; ++nt) {
        const int o = colbase + nt * 16 + l16;
        const float bs = bias[o];
        const int nh = o >> 5, kk = o & 31;
#pragma unroll
        for (int mc = 0; mc < 4; ++mc) {
            if (job == 0) {
#pragma unroll
                for (int r = 0; r < 4; ++r) {
                    const int grow = rowbase + mc * 16 + quad * 4 + r;
                    // scale = (1/sqrt(32)) * log2(e): attn uses exp2
                    const float x = (acc[mc][nt][r] + bs) * 0.25503508f;
                    const int bb = grow >> 10, mm = grow & 1023;
                    qo[(((bb * 8 + nh) * 1024 + mm) << 5) + kk] = (_Float16)x;
                }
            } else if (job == 1) {
#pragma unroll
                for (int r = 0; r < 4; ++r) {
                    const int grow = rowbase + mc * 16 + quad * 4 + r;
                    const float x = acc[mc][nt][r] + bs;
                    const int bb = grow >> 12, ii = grow & 4095;
                    ko[(((bb * 8 + nh) * 4096 + ii) << 5) + kk] = (_Float16)x;
                }
            } else {
                const int grow0 = rowbase + mc * 16 + quad * 4;
                const int bb = grow0 >> 12, i0 = grow0 & 4095;
                f16x4 pv;
#pragma unroll
                for (int r = 0; r < 4; ++r) {
                    float x = acc[mc][nt][r] + bs;
                    const float sg = 1.0f / (1.0f + __expf(-x));
                    pv[r] = (_Float16)(x * sg);
                }
                *(f16x4*)(vo + (((size_t)(bb * 8 + nh) * 32 + kk) << 12) + i0) = pv;
            }
        }
    }
}

// ---------------- attn: LDS K/V, triple-buffered counted-vmcnt pipeline -----
// grid 512 = 32 bn (XCD swizzle: bn%8==XCD) x 16 mt; block = 8 waves, 64 rows.
// wave (rg=wid&3, kc=wid>>2): q-rows [m0+rg*16,+16), keys [kc*2048,+2048).
// 2 K/V streams, each TRIPLE-buffered 64-key tiles (32 steps):
//   stream base kc*24576 + buf*8192: K tile 4 KB | V tile 4 KB.
// Per step each wave issues 2 gl_lds16 for step s+2, computes step s, then
//   s_waitcnt vmcnt(2) + s_barrier  (raw asm: __syncthreads would re-drain
//   vmcnt to 0 and kill the lookahead -- the m97 barrier-drain stall).
// K granule (k,c) -> slot k*4 + ((c + (k>>2))&3)  (conflict-free b128 reads)
// V granule (v,c) -> slot v*8 + ((c+v)&7)         (conflict-free b64 reads)
__global__ __launch_bounds__(512, 4) void attn_kernel(
    const _Float16* __restrict__ qb,   // [32][1024][32] (pre-scaled log2e/sqrt32)
    const _Float16* __restrict__ kb,   // [32][4096][32]
    const _Float16* __restrict__ vt,   // [32][32][4096]  (V^T)
    float* __restrict__ out) {         // [4][1024][256]
    __shared__ __align__(16) char pool[49152];   // 2 streams x 3 bufs x 8 KB

    const int tid = threadIdx.x;
    const int lane = tid & 63, wid = tid >> 6;
    const int quad = lane >> 4, l16 = lane & 15;
    const int bn = blockIdx.x & 31, mt = blockIdx.x >> 5;
    const int b = bn >> 3, n = bn & 7;
    const int m0 = mt * 64;
    const int rg = wid & 3, kc = wid >> 2;

    // ---- per-wave DMA assignments: 2 wave-loads (1 KB each) per step ----
    const _Float16* gsrc[2];
    int ldsoff[2], adv[2];
#pragma unroll
    for (int jj = 0; jj < 2; ++jj) {
        const int j = wid + jj * 8;              // 0..15
        const int kcj = j >> 3, sub = j & 7;
        const int gl = (sub & 3) * 64 + lane;    // granule slot in K or V region
        if (sub < 4) {   // K region: invert slot = k*4 + ((c + (k>>2))&3)
            const int k = gl >> 2, c = ((gl & 3) - (k >> 2)) & 3;
            gsrc[jj]   = kb + ((size_t)bn << 17) + (size_t)(kcj * 2048 + k) * 32 + c * 8;
            ldsoff[jj] = kcj * 24576 + gl * 16;
            adv[jj] = 2048;                      // 64 keys * 32 elems per step
        } else {         // V region: invert slot = v*8 + ((c+v)&7)
            const int v = gl >> 3, c = ((gl & 7) - v) & 7;
            gsrc[jj]   = vt + ((size_t)bn << 17) + (size_t)v * 4096 + kcj * 2048 + c * 8;
            ldsoff[jj] = kcj * 24576 + 4096 + gl * 16;
            adv[jj] = 64;                        // 64 keys per step
        }
    }

    // Q fragment (16 rows, L2-hot)
    const f16x8 qf = *(const f16x8*)(qb + (((size_t)(bn << 10) + m0 + rg * 16 + l16) << 5) + quad * 8);

    // per-lane read bases (K read swizzle is tloc-invariant by construction)
    const int kread = kc * 24576 + l16 * 64 + ((quad + (l16 >> 2)) & 3) * 16;
    const int vread = kc * 24576 + 4096 + l16 * 128 + (quad & 1) * 8;
    const int r0 = (quad >> 1) + l16;

    // prologue: DMA steps 0,1 into bufs 0,1
#pragma unroll
    for (int p = 0; p < 2; ++p)
#pragma unroll
        for (int jj = 0; jj < 2; ++jj) {
            gl_lds16(gsrc[jj], pool + ldsoff[jj] + p * 8192);
            gsrc[jj] += adv[jj];
        }
    asm volatile("s_waitcnt vmcnt(2)\n\ts_barrier" ::: "memory");   // step 0 ready

    f32x4 acc0 = (f32x4){0.f, 0.f, 0.f, 0.f};   // out^T[v=quad*4+r   ][m=rg*16+l16]
    f32x4 acc1 = acc0;                           // out^T[v=16+quad*4+r][m=rg*16+l16]
    float ps0 = 0.f;

    for (int s = 0; s < 32; ++s) {
        if (s < 30) {   // DMA step s+2 into buffer (s+2)%3
            const int nb = ((s + 2) % 3) * 8192;
#pragma unroll
            for (int jj = 0; jj < 2; ++jj) {
                gl_lds16(gsrc[jj], pool + ldsoff[jj] + nb);
                gsrc[jj] += adv[jj];
            }
        }
        const char* kbase = pool + kread + (s % 3) * 8192;
        const char* vbase = pool + vread + (s % 3) * 8192;
#pragma unroll
        for (int tloc = 0; tloc < 4; ++tloc) {
            const f16x8 kf = *(const f16x8*)(kbase + tloc * 1024);
            const int rot = ((2 * tloc + r0) & 7) * 16;
            const f16x4 va0 = *(const f16x4*)(vbase + rot);
            const f16x4 va1 = *(const f16x4*)(vbase + rot + 2048);

            f32x4 s0 = __builtin_amdgcn_mfma_f32_16x16x32_f16(kf, qf, (f32x4){0.f,0.f,0.f,0.f}, 0, 0, 0);
            const float p0 = EXP2(s0[0]), p1 = EXP2(s0[1]), p2 = EXP2(s0[2]), p3 = EXP2(s0[3]);
            ps0 += (p0 + p1) + (p2 + p3);
            auto e0 = __builtin_amdgcn_cvt_pkrtz(p0, p1);
            auto e1 = __builtin_amdgcn_cvt_pkrtz(p2, p3);
            const f16x4 pb = {F16(e0[0]), F16(e0[1]), F16(e1[0]), F16(e1[1])};
            acc0 = __builtin_amdgcn_mfma_f32_16x16x16f16(va0, pb, acc0, 0, 0, 0);
            acc1 = __builtin_amdgcn_mfma_f32_16x16x16f16(va1, pb, acc1, 0, 0, 0);
        }
        // wait for step s+1's loads (issued one full step ago), keep s+2's 2
        // loads in flight across the barrier
        if (s < 30)       asm volatile("s_waitcnt vmcnt(2)\n\ts_barrier" ::: "memory");
        else if (s == 30) asm volatile("s_waitcnt vmcnt(0)\n\ts_barrier" ::: "memory");
        else              asm volatile("s_barrier" ::: "memory");
    }

    // ---- epilogue: 2-way key-split combine in (now free) LDS ----
    float* num = (float*)pool;                 // [64][33]
    float* den = (float*)(pool + 64 * 33 * 4); // [64]
    for (int i = tid; i < 64 * 33 + 64; i += 512) ((float*)pool)[i] = 0.f;
    __syncthreads();

    // sum exp-partials over the 4 quads (score rows live in quads)
    ps0 += __shfl_xor(ps0, 16); ps0 += __shfl_xor(ps0, 32);

    const int m = rg * 16 + l16;
#pragma unroll
    for (int r = 0; r < 4; ++r) {
        atomicAdd(&num[m * 33 + quad * 4 + r], acc0[r]);
        atomicAdd(&num[m * 33 + 16 + quad * 4 + r], acc1[r]);
    }
    if (quad == 0) atomicAdd(&den[m], ps0);
    __syncthreads();

    // store: 64 m x 32 v = 2048 f32 = 512 threads x one float4
    {
        const int mloc = tid >> 3, v4 = (tid & 7) * 4;
        const float inv = 1.0f / den[mloc];
        const float* nr = num + mloc * 33 + v4;
        float4 o = {nr[0] * inv, nr[1] * inv, nr[2] * inv, nr[3] * inv};
        *(float4*)(out + (((size_t)(b << 10) + m0 + mloc) << 8) + n * 32 + v4) = o;
    }
}

// ---------------- launch -----------------------------------------------------
extern "C" void kernel_launch(void* const* d_in, const int* in_sizes, int n_in,
                              void* d_out, int out_size, void* d_ws, size_t ws_size,
                              hipStream_t stream) {
    const float* blob = (const float*)d_in[0];
    const float* wq = (const float*)d_in[1];
    const float* bq = (const float*)d_in[2];
    const float* wk = (const float*)d_in[3];
    const float* bk = (const float*)d_in[4];
    const float* wv = (const float*)d_in[5];
    const float* bv = (const float*)d_in[6];
    float* out = (float*)d_out;

    char* ws = (char*)d_ws;
    _Float16* wt = (_Float16*)(ws);                    //   393,216 B
    _Float16* ko = (_Float16*)(ws + 393216);           // 8,388,608 B
    _Float16* vo = (_Float16*)(ws + 8781824);          // 8,388,608 B
    _Float16* qo = (_Float16*)(ws + 17170432);         // 2,097,152 B

    prep_kernel<<<192, 256, 0, stream>>>(wq, wk, wv, wt);
    proj_kernel<<<576, 256, 0, stream>>>(blob, wt, bq, bk, bv, qo, ko, vo);
    attn_kernel<<<512, 512, 0, stream>>>(qo, ko, vo, out);
}